// Round 11
// baseline (222.760 us; speedup 1.0000x reference)
//
#include <hip/hip_runtime.h>

// B=8, H=8, L=2048, D=64, num_delays=16
static constexpr int LSEQ = 2048;
static constexpr int NB   = 8;
static constexpr int NH   = 8;
static constexpr int ND   = 64;
static constexpr int NDEL = 16;

// ws layout (same 8.4 MB proven-safe envelope, same w/delay offsets):
//   Pc    : float2[128 part][8 b][1024]  at 0      (exactly 8 MiB)
//           compact partial spectra: slot j in [1,1024) holds freq j;
//           slot 0 packs (Re S[0], Re S[1024]) — both freqs are purely real.
//           (reduction is now FUSED into ifft_topk — no part-0 writeback)
//   w     : float [8][16]               at 8388608
//   delay : int   [8][16]               at 8389120
static constexpr size_t WS_P_OFF     = 0;
static constexpr size_t WS_W_OFF     = 8388608;
static constexpr size_t WS_DELAY_OFF = 8389120;

// LDS bank swizzle on float2 index: fold bits 4..6 into bits 1..3.
// Touches only bits 1..3 — band bits (8..10) and 32-group bits (5..7) are
// preserved, which is what makes the intra-wave barrier elision legal.
__device__ __forceinline__ int SWZ(int x) { return x ^ (((x >> 4) & 7) << 1); }

// digit-reversed position of frequency f (radices 8,8,8,4 DIF) and inverse
__device__ __forceinline__ int pof(int f) {
    return ((f & 7) << 8) | (((f >> 3) & 7) << 5) | (((f >> 6) & 7) << 2) | (f >> 9);
}
__device__ __forceinline__ int fofp(int p) {
    return (p >> 8) | (((p >> 5) & 7) << 3) | (((p >> 2) & 7) << 6) | ((p & 3) << 9);
}

#define CMUL(ar, ai, br, bi) make_float2((ar)*(br) - (ai)*(bi), (ar)*(bi) + (ai)*(br))

// 8-pt DIF DFT in regs; x[0..7] in, X[0..7] (natural freq order) out.
__device__ __forceinline__ void dft8(const float2 x[8], float2 X[8]) {
    const float RH = 0.70710678118654752440f;
    float2 a0 = make_float2(x[0].x + x[4].x, x[0].y + x[4].y);
    float2 a1 = make_float2(x[1].x + x[5].x, x[1].y + x[5].y);
    float2 a2 = make_float2(x[2].x + x[6].x, x[2].y + x[6].y);
    float2 a3 = make_float2(x[3].x + x[7].x, x[3].y + x[7].y);
    float2 b0 = make_float2(x[0].x - x[4].x, x[0].y - x[4].y);
    float  t1r = x[1].x - x[5].x, t1i = x[1].y - x[5].y;
    float2 b1 = make_float2(RH * (t1r + t1i), RH * (t1i - t1r));       // * w8^1
    float  t2r = x[2].x - x[6].x, t2i = x[2].y - x[6].y;
    float2 b2 = make_float2(t2i, -t2r);                                // * -i
    float  t3r = x[3].x - x[7].x, t3i = x[3].y - x[7].y;
    float2 b3 = make_float2(RH * (t3i - t3r), -RH * (t3r + t3i));      // * w8^3
    float2 c0 = make_float2(a0.x + a2.x, a0.y + a2.y);
    float2 d0 = make_float2(a0.x - a2.x, a0.y - a2.y);
    float2 c1 = make_float2(a1.x + a3.x, a1.y + a3.y);
    float2 d1 = make_float2(a1.y - a3.y, -(a1.x - a3.x));              // * -i
    X[0] = make_float2(c0.x + c1.x, c0.y + c1.y);
    X[4] = make_float2(c0.x - c1.x, c0.y - c1.y);
    X[2] = make_float2(d0.x + d1.x, d0.y + d1.y);
    X[6] = make_float2(d0.x - d1.x, d0.y - d1.y);
    float2 e0 = make_float2(b0.x + b2.x, b0.y + b2.y);
    float2 f0 = make_float2(b0.x - b2.x, b0.y - b2.y);
    float2 e1 = make_float2(b1.x + b3.x, b1.y + b3.y);
    float2 f1 = make_float2(b1.y - b3.y, -(b1.x - b3.x));              // * -i
    X[1] = make_float2(e0.x + e1.x, e0.y + e1.y);
    X[5] = make_float2(e0.x - e1.x, e0.y - e1.y);
    X[3] = make_float2(f0.x + f1.x, f0.y + f1.y);
    X[7] = make_float2(f0.x - f1.x, f0.y - f1.y);
}

// 4-pt DFT: X[m] = sum_j x[j] (-i)^{jm}
__device__ __forceinline__ void dft4(const float2 x[4], float2 X[4]) {
    float2 s0 = make_float2(x[0].x + x[2].x, x[0].y + x[2].y);
    float2 s1 = make_float2(x[1].x + x[3].x, x[1].y + x[3].y);
    float2 d0 = make_float2(x[0].x - x[2].x, x[0].y - x[2].y);
    float2 d1 = make_float2(x[1].y - x[3].y, -(x[1].x - x[3].x));      // * -i
    X[0] = make_float2(s0.x + s1.x, s0.y + s1.y);
    X[2] = make_float2(s0.x - s1.x, s0.y - s1.y);
    X[1] = make_float2(d0.x + d1.x, d0.y + d1.y);
    X[3] = make_float2(d0.x - d1.x, d0.y - d1.y);
}

// in-place radix-8 stage with twiddle chain W on LDS plane zp
__device__ __forceinline__ void stageR8(float2* zp, const int adr[8], const float2 W[7]) {
    float2 X[8], Y[8];
    #pragma unroll
    for (int j = 0; j < 8; ++j) X[j] = zp[adr[j]];
    dft8(X, Y);
    #pragma unroll
    for (int m = 1; m < 8; ++m) Y[m] = CMUL(Y[m].x, Y[m].y, W[m-1].x, W[m-1].y);
    #pragma unroll
    for (int m = 0; m < 8; ++m) zp[adr[m]] = Y[m];
}

// ---------------------------------------------------------------------------
// Kernel A: round-6/7 verified pipeline (best measured 51 µs). Intra-wave
// barrier elision on B/C/D (bands owned by 32-thread clusters ⊂ one wave;
// same-wave DS ops program-ordered). 5 barriers/block. Compact partial store.
// NOTE (round-10 lesson): hipLaunchCooperativeKernel inside kernel_launch
// breaks the harness's stream/graph capture — mega-kernel fusion is closed.
// ---------------------------------------------------------------------------
__global__ __launch_bounds__(256, 2) void fft_corr(const float* __restrict__ q,
                                                   const float* __restrict__ k,
                                                   float2* __restrict__ Pc) {
    __shared__ float2 z0[LSEQ], z1[LSEQ];   // 32 KiB (swizzled)
    const int t    = threadIdx.x;
    const int bi   = blockIdx.x;            // 1024 = 8 xcd * 8 bh * 8 grp * 2 half
    const int xcd  = bi & 7;
    const int sl   = bi >> 3;               // 0..127
    const int bh   = xcd * 8 + (sl >> 4);   // b == xcd -> XCD-local chain
    const int grp  = (sl >> 1) & 7;
    const int half = sl & 1;
    const int b    = bh >> 3;
    const int h    = bh & 7;
    const size_t base = (size_t)bh * LSEQ * ND + (size_t)(grp * 8 + half * 4);

    // twiddle power chains (per thread, shared by all channels)
    float2 WA[7], WB[7], WC[7];
    {
        float sn, cs;
        __sincosf(-6.28318530717958647692f * (float)t / 2048.f, &sn, &cs);
        WA[0] = make_float2(cs, sn);
        __sincosf(-6.28318530717958647692f * (float)(t & 31) / 256.f, &sn, &cs);
        WB[0] = make_float2(cs, sn);
        __sincosf(-6.28318530717958647692f * (float)(t & 3) / 32.f, &sn, &cs);
        WC[0] = make_float2(cs, sn);
        #pragma unroll
        for (int m = 1; m < 7; ++m) {
            WA[m] = CMUL(WA[m-1].x, WA[m-1].y, WA[0].x, WA[0].y);
            WB[m] = CMUL(WB[m-1].x, WB[m-1].y, WB[0].x, WB[0].y);
            WC[m] = CMUL(WC[m-1].x, WC[m-1].y, WC[0].x, WC[0].y);
        }
    }

    // owned product slots: cc in {0,1,4,5} -> f in [0,1024)
    int fS[4], pmS[4];
    #pragma unroll
    for (int s = 0; s < 4; ++s) {
        const int cc = (s < 2) ? s : s + 2;           // {0,1,4,5}
        const int f  = fofp(8 * t + cc);
        const int m  = (2048 - f) & 2047;
        fS[s]  = f;
        pmS[s] = SWZ(pof(m));
    }
    float aFr[4] = {0, 0, 0, 0}, aFi[4] = {0, 0, 0, 0};
    float aS = 0.f;                      // f=1024 special (thread 0)

    const int sbB   = (t >> 5) * 256 + (t & 31);
    const int baseC = (t >> 2) * 32 + (t & 3);
    int adrB[8], adrC[8], adrD[8];
    #pragma unroll
    for (int n = 0; n < 8; ++n) {
        adrB[n] = SWZ(sbB + 32 * n);
        adrC[n] = SWZ(baseC + 4 * n);
        adrD[n] = SWZ(8 * t + n);
    }

    float4 qa[8], ka[8];
    #pragma unroll
    for (int j = 0; j < 8; ++j) {
        const size_t r = base + (size_t)(t + 256 * j) * ND;
        qa[j] = *(const float4*)(q + r);
        ka[j] = *(const float4*)(k + r);
    }

    float2 X0[8], X1[8], Y0[8], Y1[8];

    auto stageA = [&](int c0, int c1) {
        #pragma unroll
        for (int j = 0; j < 8; ++j) {
            X0[j] = make_float2((&qa[j].x)[c0], (&ka[j].x)[c0]);
            X1[j] = make_float2((&qa[j].x)[c1], (&ka[j].x)[c1]);
        }
        dft8(X0, Y0);
        dft8(X1, Y1);
        #pragma unroll
        for (int m = 1; m < 8; ++m) {
            Y0[m] = CMUL(Y0[m].x, Y0[m].y, WA[m-1].x, WA[m-1].y);
            Y1[m] = CMUL(Y1[m].x, Y1[m].y, WA[m-1].x, WA[m-1].y);
        }
        #pragma unroll
        for (int m = 0; m < 8; ++m) {
            const int a = SWZ(m * 256 + t);
            z0[a] = Y0[m];
            z1[a] = Y1[m];
        }
    };
    auto stageBCD = [&]() {          // intra-wave region — no barriers inside
        stageR8(z0, adrB, WB);
        stageR8(z1, adrB, WB);
        stageR8(z0, adrC, WC);
        stageR8(z1, adrC, WC);
        {
            float2 xin[8];
            #pragma unroll
            for (int j = 0; j < 8; ++j) xin[j] = z0[adrD[j]];
            dft4(&xin[0], &X0[0]);
            dft4(&xin[4], &X0[4]);
            #pragma unroll
            for (int m = 0; m < 8; ++m) z0[adrD[m]] = X0[m];
        }
        {
            float2 xin[8];
            #pragma unroll
            for (int j = 0; j < 8; ++j) xin[j] = z1[adrD[j]];
            dft4(&xin[0], &X1[0]);
            dft4(&xin[4], &X1[4]);
            #pragma unroll
            for (int m = 0; m < 8; ++m) z1[adrD[m]] = X1[m];
        }
    };
    auto product = [&]() {
        #pragma unroll
        for (int s = 0; s < 4; ++s) {
            const int cc = (s < 2) ? s : s + 2;   // {0,1,4,5}
            {
                const float2 Zf = X0[cc], Zm = z0[pmS[s]];
                const float qr = 0.5f * (Zf.x + Zm.x), qi = 0.5f * (Zf.y - Zm.y);
                const float kr = 0.5f * (Zf.y + Zm.y), ki = 0.5f * (Zm.x - Zf.x);
                aFr[s] += qr * kr + qi * ki;
                aFi[s] += qi * kr - qr * ki;
            }
            {
                const float2 Zf = X1[cc], Zm = z1[pmS[s]];
                const float qr = 0.5f * (Zf.x + Zm.x), qi = 0.5f * (Zf.y - Zm.y);
                const float kr = 0.5f * (Zf.y + Zm.y), ki = 0.5f * (Zm.x - Zf.x);
                aFr[s] += qr * kr + qi * ki;
                aFi[s] += qi * kr - qr * ki;
            }
        }
        if (t == 0) aS += X0[2].x * X0[2].y + X1[2].x * X1[2].y;
    };

    // pr = 0 (no entry barrier — planes untouched at block start)
    stageA(0, 1);
    __syncthreads();                 // A scatter complete (cross-wave)
    stageBCD();
    __syncthreads();                 // D writeback complete (mirror reads)
    product();
    __syncthreads();                 // product reads done — planes reusable
    // pr = 1
    stageA(2, 3);
    __syncthreads();
    stageBCD();
    __syncthreads();
    product();

    // compact store: Pc[part][b][f] = acc, f = fS[s] in [0,1024).
    // slot 0 packs (Re S[0], Re S[1024]); Im S[0] is mathematically 0.
    const int part = h * 16 + grp * 2 + half;        // 0..127
    float2* Pp = Pc + (size_t)part * (NB * 1024) + (size_t)b * 1024;
    #pragma unroll
    for (int s = 0; s < 4; ++s) Pp[fS[s]] = make_float2(aFr[s], aFi[s]);
    if (t == 0) Pp[0] = make_float2(aFr[0], aS);
}

// ---------------------------------------------------------------------------
// Kernel B (FUSED): per-batch block reduces its 128 compact partials straight
// into the LDS digit-rev spectrum (no reduce_S kernel, no part-0 writeback /
// re-read), then runs the verified inverse-FFT + per-wave top-16 + softmax.
// Reads are XCD-local: batch b's partials were all written from XCD b, and
// block b of an 8-block dispatch round-robins onto XCD b.
// Barriers: 5 (FFT) + 1 (cand merge).
// ---------------------------------------------------------------------------
__global__ __launch_bounds__(256) void ifft_topk(const float2* __restrict__ Pc,
                                                 float* __restrict__ wout,
                                                 int* __restrict__ dout) {
    __shared__ float2 zz[LSEQ];          // 16 KiB work (swizzled in stages)
    __shared__ float  mc[LSEQ];          // 8 KiB, natural tau order
    __shared__ float  candv[4][NDEL];
    __shared__ int    candt[4][NDEL];
    const int b = blockIdx.x, t = threadIdx.x;

    float2 WA[7], WB[7], WC[7];
    {
        float sn, cs;
        __sincosf(-6.28318530717958647692f * (float)t / 2048.f, &sn, &cs);
        WA[0] = make_float2(cs, sn);
        __sincosf(-6.28318530717958647692f * (float)(t & 31) / 256.f, &sn, &cs);
        WB[0] = make_float2(cs, sn);
        __sincosf(-6.28318530717958647692f * (float)(t & 3) / 32.f, &sn, &cs);
        WC[0] = make_float2(cs, sn);
        #pragma unroll
        for (int m = 1; m < 7; ++m) {
            WA[m] = CMUL(WA[m-1].x, WA[m-1].y, WA[0].x, WA[0].y);
            WB[m] = CMUL(WB[m-1].x, WB[m-1].y, WB[0].x, WB[0].y);
            WC[m] = CMUL(WC[m-1].x, WC[m-1].y, WC[0].x, WC[0].y);
        }
    }
    const int sbB   = (t >> 5) * 256 + (t & 31);
    const int baseC = (t >> 2) * 32 + (t & 3);
    int adrB[8], adrC[8], adrD[8];
    #pragma unroll
    for (int n = 0; n < 8; ++n) {
        adrB[n] = SWZ(sbB + 32 * n);
        adrC[n] = SWZ(baseC + 4 * n);
        adrD[n] = SWZ(8 * t + n);
    }

    // FUSED reduction: sum 128 partials for each owned column, place the
    // reduced value directly at its digit-rev slot (+ conj mirror).
    #pragma unroll
    for (int u = 0; u < 4; ++u) {
        const int j = t + 256 * u;
        const float2* col = Pc + (size_t)b * 1024 + j;
        float ax = 0.f, ay = 0.f;
        #pragma unroll 8
        for (int part = 0; part < 128; ++part) {
            const float2 v = col[(size_t)part * (NB * 1024)];
            ax += v.x; ay += v.y;
        }
        if (j == 0) {
            zz[0] = make_float2(ax, 0.f);             // pof(0)    = 0
            zz[2] = make_float2(ay, 0.f);             // pof(1024) = 2
        } else {
            zz[pof(j)]        = make_float2(ax, ay);
            zz[pof(2048 - j)] = make_float2(ax, -ay);
        }
    }
    __syncthreads();

    // gather stage-A operands: x[f] = conj(S[f]) at slot pof(f), f = t+256j
    float2 X[8], Y[8];
    #pragma unroll
    for (int j = 0; j < 8; ++j) {
        const float2 s = zz[pof(t + 256 * j)];
        X[j] = make_float2(s.x, -s.y);
    }
    __syncthreads();                     // all gathers done before scatter

    dft8(X, Y);
    #pragma unroll
    for (int m = 1; m < 8; ++m) Y[m] = CMUL(Y[m].x, Y[m].y, WA[m-1].x, WA[m-1].y);
    #pragma unroll
    for (int m = 0; m < 8; ++m) zz[SWZ(m * 256 + t)] = Y[m];
    __syncthreads();

    // B, C, D: intra-wave region (band t>>5 owned by the 32-cluster) — no
    // barriers (round-6 proof; same addressing, same SWZ).
    stageR8(zz, adrB, WB);
    stageR8(zz, adrC, WC);
    {
        float2 xin[8];
        #pragma unroll
        for (int j = 0; j < 8; ++j) xin[j] = zz[adrD[j]];
        dft4(&xin[0], &X[0]);
        dft4(&xin[4], &X[4]);
    }

    // mc[tau] = Re(out)/(L*H*D); slot 8t+cc holds tau = fofp(8t+cc)
    const float scale = 1.0f / ((float)LSEQ * (float)(NH * ND));
    #pragma unroll
    for (int cc = 0; cc < 8; ++cc) mc[fofp(8 * t + cc)] = X[cc].x * scale;
    __syncthreads();

    // ---- per-wave top-16 (wave w owns taus [512w, 512w+512), 8 regs/lane) --
    const int L = t & 63, wv = t >> 6;
    float v[8];
    #pragma unroll
    for (int u = 0; u < 8; ++u) v[u] = mc[512 * wv + 64 * u + L];

    for (int it = 0; it < NDEL; ++it) {
        // local argmax over 8 (ascending u = ascending tau -> ties keep smaller)
        float bv = v[0]; int bu = 0;
        #pragma unroll
        for (int u = 1; u < 8; ++u) if (v[u] > bv) { bv = v[u]; bu = u; }
        int bt_ = 512 * wv + 64 * bu + L;
        // wave-wide shfl reduce (ties -> smaller tau)
        #pragma unroll
        for (int off = 32; off; off >>= 1) {
            const float ov = __shfl_xor(bv, off);
            const int   ot = __shfl_xor(bt_, off);
            if (ov > bv || (ov == bv && ot < bt_)) { bv = ov; bt_ = ot; }
        }
        // owner lane clears the winner (static reg indexing)
        #pragma unroll
        for (int u = 0; u < 8; ++u)
            if (512 * wv + 64 * u + L == bt_) v[u] = -3e38f;
        if (L == 0) { candv[wv][it] = bv; candt[wv][it] = bt_; }
    }
    __syncthreads();

    // ---- merge 4 descending lists + softmax (thread 0) ----
    if (t == 0) {
        int hp[4] = {0, 0, 0, 0};
        float topv[NDEL]; int topi[NDEL];
        for (int it = 0; it < NDEL; ++it) {
            float bv = -3e38f; int bt_ = 1 << 30; int bw = 0;
            #pragma unroll
            for (int ww = 0; ww < 4; ++ww) {
                const float cv = candv[ww][hp[ww]];
                const int   ct = candt[ww][hp[ww]];
                if (cv > bv || (cv == bv && ct < bt_)) { bv = cv; bt_ = ct; bw = ww; }
            }
            topv[it] = bv; topi[it] = bt_; ++hp[bw];
        }
        const float m = topv[0];
        float e[NDEL], sum = 0.f;
        for (int i = 0; i < NDEL; ++i) { e[i] = __expf(topv[i] - m); sum += e[i]; }
        const float inv = 1.0f / sum;
        for (int i = 0; i < NDEL; ++i) {
            wout[b * NDEL + i] = e[i] * inv;
            dout[b * NDEL + i] = topi[i];
        }
    }
}

// ---------------------------------------------------------------------------
// Kernel C: out[b,h,t,d] = sum_k w[b,k] * v[b,h,(t+delay[b,k]) & 2047, d]
// XCD swizzle keeps each (b,h) v-slice L2-resident. out is write-once ->
// nontemporal stores (round-7 verified).
// ---------------------------------------------------------------------------
typedef float f4nt __attribute__((ext_vector_type(4)));

__global__ __launch_bounds__(256) void gather_out(const float* __restrict__ v,
                                                  const float* __restrict__ w,
                                                  const int* __restrict__ delay,
                                                  float* __restrict__ out) {
    const int bi  = blockIdx.x;          // 8192 = 64 bh * 128 tiles
    const int xcd = bi & 7;
    const int s   = bi >> 3;
    const int bh  = xcd * 8 + (s >> 7);
    const int bt  = s & 127;
    const int b   = bh >> 3;
    const int tid = threadIdx.x;

    __shared__ float sw_[NDEL];
    __shared__ int   sd_[NDEL];
    if (tid < NDEL) {
        sw_[tid] = w[b * NDEL + tid];
        sd_[tid] = delay[b * NDEL + tid];
    }
    __syncthreads();

    const float* vb = v + (size_t)bh * LSEQ * ND;
    float*       ob = out + (size_t)bh * LSEQ * ND;

    const int row = tid >> 4;
    const int col = (tid & 15) * 4;
    const int t   = bt * 16 + row;

    float4 acc = make_float4(0.f, 0.f, 0.f, 0.f);
    #pragma unroll
    for (int kk = 0; kk < NDEL; ++kk) {
        const int r = (t + sd_[kk]) & (LSEQ - 1);
        const float4 vv = *(const float4*)(vb + (size_t)r * ND + col);
        const float wv = sw_[kk];
        acc.x += wv * vv.x; acc.y += wv * vv.y;
        acc.z += wv * vv.z; acc.w += wv * vv.w;
    }
    f4nt val = {acc.x, acc.y, acc.z, acc.w};
    __builtin_nontemporal_store(val, (f4nt*)(ob + (size_t)t * ND + col));
}

// ---------------------------------------------------------------------------
extern "C" void kernel_launch(void* const* d_in, const int* in_sizes, int n_in,
                              void* d_out, int out_size, void* d_ws, size_t ws_size,
                              hipStream_t stream) {
    const float* q = (const float*)d_in[0];
    const float* k = (const float*)d_in[1];
    const float* v = (const float*)d_in[2];
    float* out = (float*)d_out;

    float2* Pc    = (float2*)((char*)d_ws + WS_P_OFF);
    float*  w     = (float*)((char*)d_ws + WS_W_OFF);
    int*    delay = (int*)((char*)d_ws + WS_DELAY_OFF);

    fft_corr<<<dim3(1024), dim3(256), 0, stream>>>(q, k, Pc);
    ifft_topk<<<dim3(NB), dim3(256), 0, stream>>>(Pc, w, delay);   // fused reduce
    gather_out<<<dim3(NB * NH * 128), dim3(256), 0, stream>>>(v, w, delay, out);
}